// Round 1
// baseline (219.361 us; speedup 1.0000x reference)
//
#include <hip/hip_runtime.h>
#include <hip/hip_bf16.h>
#include <hip/hip_fp16.h>
#include <cstdint>

#define N_NODES 100000
#define N_EDGES 1600000
#define FDIM 64
#define NPAIRS 200000
#define NB 391          // dst buckets: ceil(100000/256)
#define BCAP 4864       // bucket fill capacity (avg 4092, +12 sigma)
#define SSTR 5632       // bucket region stride (>= BCAP + 256*3 row padding)
#define EPB 6250        // edges per scatter block (256 blocks)

typedef __attribute__((ext_vector_type(8))) _Float16 half8;
typedef __attribute__((ext_vector_type(4))) float floatx4;

// K0: xh = fp16(x) for all 6250 blocks. Block 0 zeroes bucketCur/ovfCnt;
// blocks 1,2 pre-format w1/w2 into MFMA fragment order (WF1g/WF2g) so the
// fused k23 can load its weight fragments as contiguous b128s.
__global__ void __launch_bounds__(256) k0_prep(const float4* __restrict__ x4,
        __half* __restrict__ xh, const float* __restrict__ w1,
        const float* __restrict__ w2, __half* __restrict__ WF1g,
        __half* __restrict__ WF2g, int* __restrict__ bucketCur,
        int* __restrict__ ovfCnt) {
    int blk = blockIdx.x, tid = threadIdx.x;
    int i = blk * 256 + tid;                 // exactly 1.6M threads
    float4 v = x4[i];
    ushort4 o;
    o.x = __half_as_ushort(__float2half(v.x));
    o.y = __half_as_ushort(__float2half(v.y));
    o.z = __half_as_ushort(__float2half(v.z));
    o.w = __half_as_ushort(__float2half(v.w));
    ((ushort4*)xh)[i] = o;
    if (blk == 0) {
        for (int j = tid; j < NB; j += 256) bucketCur[j] = 0;
        if (tid == 0) ovfCnt[0] = 0;
    } else if (blk <= 2) {
        const float* w = (blk == 1) ? w1 : w2;
        __half* dw = (blk == 1) ? WF1g : WF2g;
        for (int f = tid; f < 512; f += 256) {
            int lane = f & 63, st = f >> 6;
            int t = st & 3, kh = st >> 2;
            int q = lane >> 4, nl = lane & 15;
            int n = t * 16 + nl;
            int K0 = kh * 32 + q * 8;
            half8 hv;
#pragma unroll
            for (int j = 0; j < 8; ++j) hv[j] = (_Float16)w[(K0 + j) * 64 + n];
            ((half8*)dw)[f] = hv;
        }
    }
}

// P1c: self-contained scatter. Per block: LDS-histogram own 6250 dsts,
// reserve per-bucket ranges via ONE global atomicAdd per bucket (order
// within a bucket is irrelevant -- p2 counting-sorts), then scatter packed
// (dlow<<17 | src). Replaces the old k0-hist + matrix + p1b scan.
__global__ void __launch_bounds__(1024) p1c_scatter(const int* __restrict__ src,
        const int* __restrict__ dst, int* __restrict__ bucketArr,
        int* __restrict__ bucketCur, int* __restrict__ ovfCnt,
        int2* __restrict__ ovfList) {
    __shared__ int hist[NB];
    __shared__ int cur[NB];
    int tid = threadIdx.x, blk = blockIdx.x;
    for (int i = tid; i < NB; i += 1024) hist[i] = 0;
    __syncthreads();
    int base = blk * EPB;
    for (int i = tid; i < EPB; i += 1024)
        atomicAdd(&hist[dst[base + i] >> 8], 1);
    __syncthreads();
    for (int b = tid; b < NB; b += 1024)
        cur[b] = atomicAdd(&bucketCur[b], hist[b]);
    __syncthreads();
    for (int i = tid; i < EPB; i += 1024) {
        int e = base + i;
        int s = src[e], d = dst[e];
        int b = d >> 8;
        int pos = atomicAdd(&cur[b], 1);
        if (pos < BCAP) {
            bucketArr[(size_t)b * SSTR + pos] = ((d & 255) << 17) | s;
        } else {
            int idx = atomicAdd(ovfCnt, 1);
            ovfList[idx] = make_int2(d, s);
        }
    }
}

// P2: per-bucket fine counting sort IN-PLACE (unchanged).
__global__ void __launch_bounds__(256) p2_build(int* __restrict__ bucketArr,
        const int* __restrict__ bucketCnt, int* __restrict__ rowptr,
        int* __restrict__ deg) {
    __shared__ int ebuf[BCAP];               // 19.5 KB
    __shared__ int hist[256], sc[256], cur[256];
    int b = blockIdx.x, t = threadIdx.x;
    int cnt = bucketCnt[b];
    if (cnt > BCAP) cnt = BCAP;
    int* arr = bucketArr + (size_t)b * SSTR;
    hist[t] = 0;
    __syncthreads();
    for (int i = t; i < cnt; i += 256) {
        int e = arr[i];
        ebuf[i] = e;
        atomicAdd(&hist[(e >> 17) & 255], 1);
    }
    __syncthreads();
    int h = hist[t];
    int pc = (h + 3) & ~3;                   // pad row to 4 ints
    sc[t] = pc;
    __syncthreads();
    for (int off = 1; off < 256; off <<= 1) {
        int u = (t >= off) ? sc[t - off] : 0;
        __syncthreads();
        sc[t] += u;
        __syncthreads();
    }
    int rbase = sc[t] - pc;                  // exclusive padded prefix
    cur[t] = rbase;
    int n = (b << 8) + t;
    if (n < N_NODES) {
        rowptr[n] = b * SSTR + rbase;
        deg[n] = h;
    }
    __syncthreads();
    for (int i = t; i < cnt; i += 256) {
        int e = ebuf[i];
        int dl = (e >> 17) & 255;
        int pos = atomicAdd(&cur[dl], 1);
        arr[pos] = e & 0x1FFFF;
    }
}

__device__ __forceinline__ void addrow(float4& acc, const __half* __restrict__ xh,
                                       int s, int fq) {
    float2 raw = *(const float2*)(xh + (size_t)s * 64 + fq * 4);
    __half2 a = *(__half2*)&raw.x;
    __half2 b = *(__half2*)&raw.y;
    float2 fa = __half22float2(a);
    float2 fb = __half22float2(b);
    acc.x += fa.x; acc.y += fa.y; acc.z += fb.x; acc.w += fb.y;
}

// K23: fused aggregation + node MLP. Block b owns nodes 16b..16b+15 --
// exactly one MFMA tile. Phase A = k2's proven 16-deep gather loop, result
// written to LDS (no h0h round-trip). Phase B = the MLP split across the
// block's 4 waves: wave w computes output col-tile w for both layers, with
// the ReLU intermediate transposed through LDS T. Weight fragments come
// pre-formatted from WF1g/WF2g (4 contiguous b128 loads per lane, issued
// at kernel start so they hide under phase A's gathers).
__global__ void __launch_bounds__(256) k23_agg_mlp(const __half* __restrict__ xh,
        __half* __restrict__ hh, const int* __restrict__ deg,
        const int* __restrict__ rowptr, const int* __restrict__ csr,
        const int* __restrict__ ovfCnt, const int2* __restrict__ ovfList,
        const float* __restrict__ x, const __half* __restrict__ WF1g,
        const __half* __restrict__ WF2g, const float* __restrict__ b1,
        const float* __restrict__ b2) {
    __shared__ __half h0s[16][72];           // pad 72: 2-way-max bank alias
    __shared__ float T[16][68];              // pad 68: float4-aligned rows
    int tid = threadIdx.x;
    int gid = blockIdx.x * 256 + tid;
    int n = gid >> 4, fq = gid & 15;
    int lane = tid & 63, w = tid >> 6;
    int q = lane >> 4, p = lane & 15;
    const half8* W1v = (const half8*)WF1g;
    const half8* W2v = (const half8*)WF2g;
    half8 wf1a = W1v[w * 64 + lane], wf1b = W1v[(4 + w) * 64 + lane];
    half8 wf2a = W2v[w * 64 + lane], wf2b = W2v[(4 + w) * 64 + lane];
    float b1v = b1[w * 16 + p], b2v = b2[w * 16 + p];

    // ---- phase A: GIN aggregation (h0 = 2x + sum of neighbor rows) ----
    int dc = deg[n];
    const int4* srow = (const int4*)(csr + rowptr[n]);
    float2 raw = *(const float2*)(xh + (size_t)n * 64 + fq * 4);
    __half2 sa = *(__half2*)&raw.x;
    __half2 sb = *(__half2*)&raw.y;
    float2 fa = __half22float2(sa);
    float2 fb = __half22float2(sb);
    float4 acc = {2.f * fa.x, 2.f * fa.y, 2.f * fb.x, 2.f * fb.y};
    int oc = ovfCnt[0];
    if (oc > 0) {                            // correctness-only path
        for (int i = 0; i < oc; ++i) {
            int2 e = ovfList[i];
            if (e.x == n) {
                const float* xr = x + (size_t)e.y * 64 + fq * 4;
                acc.x += xr[0]; acc.y += xr[1]; acc.z += xr[2]; acc.w += xr[3];
            }
        }
    }
    for (int i = 0; i < dc; i += 16) {
        int4 s4 = srow[i >> 2];
        int4 s5, s6, s7;
        if (i + 4 < dc)  s5 = srow[(i >> 2) + 1];
        if (i + 8 < dc)  s6 = srow[(i >> 2) + 2];
        if (i + 12 < dc) s7 = srow[(i >> 2) + 3];
        addrow(acc, xh, s4.x, fq);
        if (i + 1 < dc)  addrow(acc, xh, s4.y, fq);
        if (i + 2 < dc)  addrow(acc, xh, s4.z, fq);
        if (i + 3 < dc)  addrow(acc, xh, s4.w, fq);
        if (i + 4 < dc)  addrow(acc, xh, s5.x, fq);
        if (i + 5 < dc)  addrow(acc, xh, s5.y, fq);
        if (i + 6 < dc)  addrow(acc, xh, s5.z, fq);
        if (i + 7 < dc)  addrow(acc, xh, s5.w, fq);
        if (i + 8 < dc)  addrow(acc, xh, s6.x, fq);
        if (i + 9 < dc)  addrow(acc, xh, s6.y, fq);
        if (i + 10 < dc) addrow(acc, xh, s6.z, fq);
        if (i + 11 < dc) addrow(acc, xh, s6.w, fq);
        if (i + 12 < dc) addrow(acc, xh, s7.x, fq);
        if (i + 13 < dc) addrow(acc, xh, s7.y, fq);
        if (i + 14 < dc) addrow(acc, xh, s7.z, fq);
        if (i + 15 < dc) addrow(acc, xh, s7.w, fq);
    }
    ushort4 st4;
    st4.x = __half_as_ushort(__float2half(acc.x));
    st4.y = __half_as_ushort(__float2half(acc.y));
    st4.z = __half_as_ushort(__float2half(acc.z));
    st4.w = __half_as_ushort(__float2half(acc.w));
    *(ushort4*)&h0s[n & 15][fq * 4] = st4;
    __syncthreads();

    // ---- phase B: node MLP, wave w owns output col-tile w ----
    half8 A0 = *(const half8*)&h0s[p][q * 8];
    half8 A1 = *(const half8*)&h0s[p][32 + q * 8];
    floatx4 acc1 = (floatx4){0.f, 0.f, 0.f, 0.f};
    acc1 = __builtin_amdgcn_mfma_f32_16x16x32_f16(A0, wf1a, acc1, 0, 0, 0);
    acc1 = __builtin_amdgcn_mfma_f32_16x16x32_f16(A1, wf1b, acc1, 0, 0, 0);
#pragma unroll
    for (int r = 0; r < 4; ++r)
        T[q * 4 + r][w * 16 + p] = fmaxf(acc1[r] + b1v, 0.f);
    __syncthreads();
    float4 u0 = *(const float4*)&T[p][q * 8];
    float4 u1 = *(const float4*)&T[p][q * 8 + 4];
    float4 u2 = *(const float4*)&T[p][32 + q * 8];
    float4 u3 = *(const float4*)&T[p][32 + q * 8 + 4];
    half8 g0, g1;
    g0[0] = (_Float16)u0.x; g0[1] = (_Float16)u0.y;
    g0[2] = (_Float16)u0.z; g0[3] = (_Float16)u0.w;
    g0[4] = (_Float16)u1.x; g0[5] = (_Float16)u1.y;
    g0[6] = (_Float16)u1.z; g0[7] = (_Float16)u1.w;
    g1[0] = (_Float16)u2.x; g1[1] = (_Float16)u2.y;
    g1[2] = (_Float16)u2.z; g1[3] = (_Float16)u2.w;
    g1[4] = (_Float16)u3.x; g1[5] = (_Float16)u3.y;
    g1[6] = (_Float16)u3.z; g1[7] = (_Float16)u3.w;
    floatx4 acc2 = (floatx4){0.f, 0.f, 0.f, 0.f};
    acc2 = __builtin_amdgcn_mfma_f32_16x16x32_f16(g0, wf2a, acc2, 0, 0, 0);
    acc2 = __builtin_amdgcn_mfma_f32_16x16x32_f16(g1, wf2b, acc2, 0, 0, 0);
    int n0 = blockIdx.x << 4;
#pragma unroll
    for (int r = 0; r < 4; ++r)
        hh[(size_t)(n0 + q * 4 + r) * 64 + w * 16 + p] =
            __float2half(fmaxf(acc2[r] + b2v, 0.f));
}

// K4: pair decoder. Ws folded into W1/W2 at staging: feat@dw1 =
// e1@(Ws+W1) + e2@(Ws+W2) + (e1.*e2)@Wp -> 6 sections, 24 MFMA/task
// (was 8 sections / 32 MFMA). 782 blocks -> 6256 waves, 2 tasks/wave.
__global__ void __launch_bounds__(512) k4_pair(const __half* __restrict__ hh,
                        const int* __restrict__ qidx,
                        const float* __restrict__ dw1, const float* __restrict__ db1,
                        const float* __restrict__ dw2, const float* __restrict__ db2,
                        float* __restrict__ out, int numWaves) {
    __shared__ half8 BF[1536];   // [s(6)][t(4)][lane(64)] -> 24 KB
    int tid = threadIdx.x;
    for (int f = tid; f < 1536; f += 512) {
        int lane = f & 63, st = f >> 6;
        int t = st & 3, s = st >> 2;         // s in [0,6)
        int sec = s >> 1, kh = s & 1;
        int q = lane >> 4, nl = lane & 15;
        int n = t * 16 + nl;
        int K0 = kh * 32 + q * 8;
        half8 hv;
#pragma unroll
        for (int j = 0; j < 8; ++j) {
            int k = K0 + j;
            float v;
            if (sec == 0)      v = dw1[k * 64 + n] + dw1[(128 + k) * 64 + n];
            else if (sec == 1) v = dw1[k * 64 + n] + dw1[(192 + k) * 64 + n];
            else               v = dw1[(64 + k) * 64 + n];
            hv[j] = (_Float16)v;
        }
        BF[f] = hv;
    }
    __syncthreads();
    int lane = tid & 63;
    int q = lane >> 4, nl = lane & 15;
    float db1t[4], dw2t[4];
#pragma unroll
    for (int t = 0; t < 4; ++t) {
        db1t[t] = db1[t * 16 + nl];
        dw2t[t] = dw2[t * 16 + nl];
    }
    float db2v = db2[0];
    int wid = (blockIdx.x * 512 + tid) >> 6;
    for (int task = wid; task < NPAIRS / 16; task += numWaves) {
        int p0 = task * 16;
        int i1 = qidx[p0 + nl];
        int i2 = qidx[NPAIRS + p0 + nl];
        const half8* r1 = (const half8*)(hh + (size_t)i1 * 64);
        const half8* r2 = (const half8*)(hh + (size_t)i2 * 64);
        half8 e1a = r1[q],     e1b = r1[4 + q];
        half8 e2a = r2[q],     e2b = r2[4 + q];
        half8 pA = e1a * e2a,  pB = e1b * e2b;    // v_pk_mul_f16
        floatx4 acc[4];
#pragma unroll
        for (int t = 0; t < 4; ++t) acc[t] = (floatx4){0.f, 0.f, 0.f, 0.f};

#define DO_STEP(S, AV)                                                        \
        _Pragma("unroll")                                                     \
        for (int t = 0; t < 4; ++t)                                           \
            acc[t] = __builtin_amdgcn_mfma_f32_16x16x32_f16(                  \
                (AV), BF[((S) * 4 + t) * 64 + lane], acc[t], 0, 0, 0);

        DO_STEP(0, e1a)  // e1 @ (Ws+W1), k 0..31
        DO_STEP(1, e1b)  // e1 @ (Ws+W1), k 32..63
        DO_STEP(2, e2a)  // e2 @ (Ws+W2)
        DO_STEP(3, e2b)
        DO_STEP(4, pA)   // (e1.*e2) @ Wp
        DO_STEP(5, pB)
#undef DO_STEP

        float part[4] = {0.f, 0.f, 0.f, 0.f};
#pragma unroll
        for (int t = 0; t < 4; ++t) {
#pragma unroll
            for (int r = 0; r < 4; ++r)
                part[r] = fmaf(fmaxf(acc[t][r] + db1t[t], 0.f), dw2t[t], part[r]);
        }
#pragma unroll
        for (int off = 1; off < 16; off <<= 1) {
#pragma unroll
            for (int r = 0; r < 4; ++r) part[r] += __shfl_xor(part[r], off, 64);
        }
        if (nl == 0) {
#pragma unroll
            for (int r = 0; r < 4; ++r) out[p0 + q * 4 + r] = part[r] + db2v;
        }
    }
}

extern "C" void kernel_launch(void* const* d_in, const int* in_sizes, int n_in,
                              void* d_out, int out_size, void* d_ws, size_t ws_size,
                              hipStream_t stream) {
    const float* x    = (const float*)d_in[0];   // [N,64]
    const int*   eidx = (const int*)d_in[1];     // [2,E]
    const int*   qidx = (const int*)d_in[3];     // [2,P]
    const float* w1   = (const float*)d_in[4];
    const float* b1   = (const float*)d_in[5];
    const float* w2   = (const float*)d_in[6];
    const float* b2   = (const float*)d_in[7];
    const float* dw1  = (const float*)d_in[8];   // [256,64]
    const float* db1  = (const float*)d_in[9];
    const float* dw2  = (const float*)d_in[10];  // [64]
    const float* db2  = (const float*)d_in[11];  // [1]
    float* out = (float*)d_out;                  // [P]

    // ws layout (<=48.41 MB; 16B aligned):
    //   hh (fp16)  @ 0          : 12,800,000 B   (MLP output, k4 input)
    //   xh (fp16)  @ 12,800,000 : 12,800,000 B   (fp16 features)
    //   bucketArr  @ 25,600,000 :  8,808,448 B
    //   ovfList    @ 34,408,448 : 12,800,000 B
    //   rowptr     @ 47,208,448 :    400,000 B
    //   deg        @ 47,608,448 :    400,000 B
    //   WF1g       @ 48,008,448 :      8,192 B   (w1 in fragment order)
    //   WF2g       @ 48,016,640 :      8,192 B
    //   bucketCur  @ 48,408,832 :      1,564 B
    //   ovfCnt     @ 48,410,396 :          4 B
    char* ws = (char*)d_ws;
    __half* hh        = (__half*)ws;
    __half* xh        = (__half*)(ws + 12800000);
    int*    bucketArr = (int*)(ws + 25600000);
    int2*   ovfList   = (int2*)(ws + 34408448);
    int*    rowptr    = (int*)(ws + 47208448);
    int*    deg       = (int*)(ws + 47608448);
    __half* WF1g      = (__half*)(ws + 48008448);
    __half* WF2g      = (__half*)(ws + 48016640);
    int*    bucketCur = (int*)(ws + 48408832);
    int*    ovfCnt    = (int*)(ws + 48410396);

    const int* src = eidx;
    const int* dst = eidx + N_EDGES;

    k0_prep<<<6250, 256, 0, stream>>>((const float4*)x, xh, w1, w2,
                                      WF1g, WF2g, bucketCur, ovfCnt);
    p1c_scatter<<<256, 1024, 0, stream>>>(src, dst, bucketArr, bucketCur,
                                          ovfCnt, ovfList);
    p2_build<<<NB, 256, 0, stream>>>(bucketArr, bucketCur, rowptr, deg);
    k23_agg_mlp<<<6250, 256, 0, stream>>>(xh, hh, deg, rowptr, bucketArr,
                                          ovfCnt, ovfList, x, WF1g, WF2g, b1, b2);
    // K4: 782 blocks x 8 waves = 6256 waves -> exactly 2 tasks/wave
    k4_pair<<<782, 512, 0, stream>>>(hh, qidx, dw1, db1, dw2, db2, out, 6256);
}